// Round 7
// baseline (6202.951 us; speedup 1.0000x reference)
//
#include <hip/hip_runtime.h>
#include <hip/hip_bf16.h>
#include <stdint.h>

// SubLSTM: T=512, B=64, I=1024, H=1024, G=4096
// Persistent cooperative kernel. Round-7:
//   - REVERT to round-4 tagged h-exchange (8B words (2bf16)<<32|tag, 2-slot
//     rotation, relaxed agent atomics, NO ordering waits in the loop —
//     the poison arc (r5/r6) put store-acks on the critical path).
//   - K-SPLIT-8: wave w owns K-slice [w*256,(w+1)*256) for ALL 4 gates.
//     A-fragments read ONCE per slice (was 4x redundant). New LDS layout
//     frag[s][lane] (s = K-slot of 32, lane-entry = row|ksub) with per-slot
//     XOR perm -> every stage write and frag read is 64 consecutive
//     permuted 16B slots = conflict-free by construction.
//   - WAVE SPECIALIZATION: waves 0-3 (x-slices) MFMA while waves 4-7 poll
//     h_t -> x-compute hidden under the exchange latency.
// 256 blocks = 4 batch-groups(16 rows) x 64 unit-groups(16 units).

#define T_STEPS 512
#define NBLK 256

typedef short bf16x8 __attribute__((ext_vector_type(8)));
typedef float f32x4 __attribute__((ext_vector_type(4)));
typedef unsigned int u32x4 __attribute__((ext_vector_type(4)));

// ---- ws layout (bytes) ----
#define WS_XBF    0
#define WS_WCAT   67108864
#define WS_HBUF   83886080          // 2 slots x 64 rows x 512 words x 8B
#define WS_NEEDED (83886080 + 524288 + 256)

// ---- LDS layout (bytes) ----
#define LDS_XBUF  0        // x frags, 2 x 32KB double buffer
#define LDS_HFRAG 65536    // h frags, 32KB
#define LDS_GSM   98304    // gate partials, 8 waves x 4 gates x 256 f32 = 32KB
#define LDS_SIZE  131072

__device__ __forceinline__ ushort f2bf(float f) {
  uint32_t u = __float_as_uint(f);
  uint32_t r = (u + 0x7fffu + ((u >> 16) & 1u)) >> 16;
  return (ushort)r;
}

__device__ __forceinline__ float sigmoid_f(float x) {
  float e = __builtin_amdgcn_exp2f(-1.44269504f * x);
  return __builtin_amdgcn_rcpf(1.0f + e);
}

// 16B load bypassing L1+L2 (reads the coherence point / MALL).
__device__ __forceinline__ u32x4 poll_load16(const void* p) {
  u32x4 v;
  asm volatile("global_load_dwordx4 %0, %1, off sc0 sc1"
               : "=v"(v) : "v"(p));
  return v;
}
#define POLL_FENCE() do {                            \
    asm volatile("s_waitcnt vmcnt(0)" ::: "memory"); \
    __builtin_amdgcn_sched_barrier(0);               \
  } while (0)

__global__ void cvt_bf16_kernel(const float* __restrict__ src,
                                ushort* __restrict__ dst, int n4) {
  int i = blockIdx.x * 256 + threadIdx.x;
  if (i >= n4) return;
  float4 v = ((const float4*)src)[i];
  ushort4 o;
  o.x = f2bf(v.x); o.y = f2bf(v.y); o.z = f2bf(v.z); o.w = f2bf(v.w);
  ((ushort4*)dst)[i] = o;
}

// W_cat[g][0:1024] = W_in[g][:], W_cat[g][1024:2048] = W_rec[g][:]
__global__ void build_wcat_kernel(const float* __restrict__ w_in,
                                  const float* __restrict__ w_rec,
                                  ushort* __restrict__ wc) {
  int i = blockIdx.x * 256 + threadIdx.x;
  if (i >= (4096 * 2048) / 4) return;
  int col4 = i & 511;
  int g = i >> 9;
  const float* src = (col4 < 256) ? (w_in + (size_t)g * 1024 + col4 * 4)
                                  : (w_rec + (size_t)g * 1024 + (col4 - 256) * 4);
  float4 v = *(const float4*)src;
  ushort4 o;
  o.x = f2bf(v.x); o.y = f2bf(v.y); o.z = f2bf(v.z); o.w = f2bf(v.w);
  ((ushort4*)wc)[i] = o;
}

// slot0 <- h0 with tag 0; slot1 <- poison tag (never matches; tags 0..512)
__global__ void init_hbuf_kernel(const float* __restrict__ h0,
                                 unsigned long long* __restrict__ hb) {
  int i = blockIdx.x * 256 + threadIdx.x;  // 0..65535
  if (i >= 65536) return;
  if (i < 32768) {
    int row = i >> 9, u2 = i & 511;
    unsigned lo = f2bf(h0[(size_t)row * 1024 + u2 * 2]);
    unsigned hi = f2bf(h0[(size_t)row * 1024 + u2 * 2 + 1]);
    hb[i] = ((unsigned long long)((hi << 16) | lo) << 32) | 0ull;
  } else {
    hb[i] = 0xFFFFFFFFull;
  }
}

__launch_bounds__(512, 2)
__global__ void sublstm_main(const ushort* __restrict__ xb,
                             const ushort* __restrict__ wc,
                             unsigned long long* __restrict__ hb,
                             const float* __restrict__ c0,
                             const float* __restrict__ bias,
                             float* __restrict__ out) {
  extern __shared__ unsigned char smem[];
  float* gsm = (float*)(smem + LDS_GSM);

  const int tid  = threadIdx.x;
  const int lane = tid & 63;
  const int w    = tid >> 6;          // K-slice wave 0..7 (0-3 = x, 4-7 = h)
  const int bid  = blockIdx.x;
  const int b0   = (bid & 3) * 16;
  const int j0   = (bid >> 2) * 16;

  // ---- persistent weights: bfrag[gate n][k8]: W row n*1024+j0+(lane&15),
  //      k = w*256 + k8*32 + (lane>>4)*8  (32 frags = 128 VGPR) ----
  bf16x8 bfrag[4][8];
  {
    const ushort* wbase =
        wc + (size_t)(j0 + (lane & 15)) * 2048 + w * 256 + ((lane >> 4) * 8);
#pragma unroll
    for (int n = 0; n < 4; ++n)
#pragma unroll
      for (int k8 = 0; k8 < 8; ++k8)
        bfrag[n][k8] = *(const bf16x8*)(wbase + (size_t)n * 1024 * 2048 + k8 * 32);
  }

  // ---- cell state + bias (threads 0..255: (batch bb, unit uu)) ----
  const int bb = tid >> 4, uu = tid & 15;
  float c_reg = 0.f;
  float bias_r0 = 0.f, bias_r1 = 0.f, bias_r2 = 0.f, bias_r3 = 0.f;
  if (tid < 256) {
    c_reg = c0[(size_t)(b0 + bb) * 1024 + j0 + uu];
    bias_r0 = bias[0 * 1024 + j0 + uu];
    bias_r1 = bias[1 * 1024 + j0 + uu];
    bias_r2 = bias[2 * 1024 + j0 + uu];
    bias_r3 = bias[3 * 1024 + j0 + uu];
  }

  // ---- h-wave poll addressing: thread hw: row b0+(hw&15), col-group hw>>4 ----
  const int hw   = tid & 255;        // used only by waves 4-7
  const int prow = hw & 15;
  const int cg   = hw >> 4;          // 0..15

  // ---- x staging: thread stages row b0+(tid&15), 16B chunks m=(tid>>4)+32j;
  //      dest frag slot s=m>>2, entry e=(m&3)*16+(tid&15) (== lane per wave)
  //      -> conflict-free ----
  const int xsrow = tid & 15;
  const int xm0   = tid >> 4;

#define STAGE_X(tt, buf)                                                      \
  do {                                                                        \
    const unsigned char* xrow = (const unsigned char*)xb +                    \
        ((size_t)(tt) * 64 + b0 + xsrow) * 2048;                              \
    _Pragma("unroll")                                                         \
    for (int j = 0; j < 4; ++j) {                                             \
      int m = xm0 + 32 * j;                                                   \
      uint4 v = *(const uint4*)(xrow + m * 16);                               \
      int s = m >> 2;                                                         \
      int e = (m & 3) * 16 + xsrow;                                           \
      *(uint4*)(smem + (buf) * 32768 + s * 1024 + ((e ^ (s & 7)) << 4)) = v;  \
    }                                                                         \
  } while (0)

  // ---- prologue: stage x_0 into buffer 0 ----
  STAGE_X(0, 0);
  __syncthreads();

  for (int t = 0; t < T_STEPS; ++t) {
    f32x4 acc0 = {0,0,0,0}, acc1 = {0,0,0,0}, acc2 = {0,0,0,0}, acc3 = {0,0,0,0};

    if (w < 4) {
      // ---- x-waves: MFMA x K-slice NOW (no h dependency) ----
      const int xbase = (t & 1) * 32768;
      bf16x8 a[8];
#pragma unroll
      for (int k8 = 0; k8 < 8; ++k8) {
        int s = w * 8 + k8;
        a[k8] = *(const bf16x8*)(smem + xbase + s * 1024 + ((lane ^ (s & 7)) << 4));
      }
#pragma unroll
      for (int k8 = 0; k8 < 8; ++k8) {
        acc0 = __builtin_amdgcn_mfma_f32_16x16x32_bf16(a[k8], bfrag[0][k8], acc0, 0, 0, 0);
        acc1 = __builtin_amdgcn_mfma_f32_16x16x32_bf16(a[k8], bfrag[1][k8], acc1, 0, 0, 0);
        acc2 = __builtin_amdgcn_mfma_f32_16x16x32_bf16(a[k8], bfrag[2][k8], acc2, 0, 0, 0);
        acc3 = __builtin_amdgcn_mfma_f32_16x16x32_bf16(a[k8], bfrag[3][k8], acc3, 0, 0, 0);
      }
    } else {
      // ---- h-waves: poll h_t (tagged words), stage to frag layout ----
      const unsigned long long* rowp =
          hb + ((t & 1) << 15) + (size_t)(b0 + prow) * 512;
      u32x4 vv[16];
#pragma unroll
      for (int g = 0; g < 8; ++g) {
        vv[2 * g]     = poll_load16(rowp + 4 * (cg + 16 * g));
        vv[2 * g + 1] = poll_load16(rowp + 4 * (cg + 16 * g) + 2);
      }
      POLL_FENCE();
      for (;;) {
        unsigned np = 0;
#pragma unroll
        for (int i = 0; i < 16; ++i)
          if (vv[i].x != (unsigned)t || vv[i].z != (unsigned)t) np |= (1u << i);
        if (!np) break;
        __builtin_amdgcn_s_sleep(1);
#pragma unroll
        for (int g = 0; g < 8; ++g) {
          if (np & (1u << (2 * g)))
            vv[2 * g] = poll_load16(rowp + 4 * (cg + 16 * g));
          if (np & (1u << (2 * g + 1)))
            vv[2 * g + 1] = poll_load16(rowp + 4 * (cg + 16 * g) + 2);
        }
        POLL_FENCE();
      }
      // stage: per g, 16B = units 8q..8q+7 of row prow (q = cg+16g)
#pragma unroll
      for (int g = 0; g < 8; ++g) {
        int q = cg + 16 * g;
        int s = q >> 2;
        int e = (q & 3) * 16 + prow;
        u32x4 d;
        d.x = vv[2 * g].y;     d.y = vv[2 * g].w;
        d.z = vv[2 * g + 1].y; d.w = vv[2 * g + 1].w;
        *(u32x4*)(smem + LDS_HFRAG + s * 1024 + ((e ^ (s & 7)) << 4)) = d;
      }
    }
    __syncthreads();   // syncA: h staged; x acc computed

    if (w >= 4) {
      // ---- h-waves: MFMA h K-slice ----
      bf16x8 a[8];
#pragma unroll
      for (int k8 = 0; k8 < 8; ++k8) {
        int s = (w - 4) * 8 + k8;
        a[k8] = *(const bf16x8*)(smem + LDS_HFRAG + s * 1024 + ((lane ^ (s & 7)) << 4));
      }
#pragma unroll
      for (int k8 = 0; k8 < 8; ++k8) {
        acc0 = __builtin_amdgcn_mfma_f32_16x16x32_bf16(a[k8], bfrag[0][k8], acc0, 0, 0, 0);
        acc1 = __builtin_amdgcn_mfma_f32_16x16x32_bf16(a[k8], bfrag[1][k8], acc1, 0, 0, 0);
        acc2 = __builtin_amdgcn_mfma_f32_16x16x32_bf16(a[k8], bfrag[2][k8], acc2, 0, 0, 0);
        acc3 = __builtin_amdgcn_mfma_f32_16x16x32_bf16(a[k8], bfrag[3][k8], acc3, 0, 0, 0);
      }
    }

    // ---- gate partials -> gsm[w][gate][cell] (post-syncA: epilogue(t-1)
    //      readers are past syncA via program order) ----
#pragma unroll
    for (int r = 0; r < 4; ++r) {
      int cell = ((lane >> 4) * 4 + r) * 16 + (lane & 15);
      gsm[w * 1024 + 0 * 256 + cell] = acc0[r];
      gsm[w * 1024 + 1 * 256 + cell] = acc1[r];
      gsm[w * 1024 + 2 * 256 + cell] = acc2[r];
      gsm[w * 1024 + 3 * 256 + cell] = acc3[r];
    }

    // ---- stage x_{t+1} (all threads; reads of that buffer start after
    //      syncB via barrier ordering) ----
    if (t + 1 < T_STEPS) STAGE_X(t + 1, (t + 1) & 1);

    __syncthreads();   // syncB: all partials in; x_{t+1} staged

    // ---- cell update; publish h FIRST, then out (threads 0..255) ----
    if (tid < 256) {
      float p0 = bias_r0, p1 = bias_r1, p2 = bias_r2, p3 = bias_r3;
#pragma unroll
      for (int ww = 0; ww < 8; ++ww) {
        p0 += gsm[ww * 1024 + 0 * 256 + tid];
        p1 += gsm[ww * 1024 + 1 * 256 + tid];
        p2 += gsm[ww * 1024 + 2 * 256 + tid];
        p3 += gsm[ww * 1024 + 3 * 256 + tid];
      }
      float g_in  = sigmoid_f(p0);
      float g_out = sigmoid_f(p1);
      float g_z   = sigmoid_f(p2);
      float g_f   = sigmoid_f(p3);
      c_reg = c_reg * g_f + g_z - g_in;
      float h_new = sigmoid_f(c_reg) - g_out;

      unsigned hbits = (unsigned)f2bf(h_new);
      unsigned pv = (unsigned)__shfl_xor((int)hbits, 1);
      if ((uu & 1) == 0) {
        unsigned hi32 = (pv << 16) | hbits;
        int wi = ((1 - (t & 1)) << 15) + (b0 + bb) * 512 + ((j0 + uu) >> 1);
        __hip_atomic_store(&hb[wi],
                           ((unsigned long long)hi32 << 32) |
                               (unsigned long long)(unsigned)(t + 1),
                           __ATOMIC_RELAXED, __HIP_MEMORY_SCOPE_AGENT);
      }
      size_t oidx = (size_t)(b0 + bb) * 1024 + j0 + uu;
      out[(size_t)t * 65536 + oidx] = h_new;
      if (t == T_STEPS - 1) {
        out[(size_t)T_STEPS * 65536 + oidx] = h_new;           // hT
        out[(size_t)T_STEPS * 65536 + 65536 + oidx] = c_reg;   // cT
      }
    }
    // no loop-end barrier: next step's gsm writes are post-syncA(t+1);
    // h-frag restage is pre-syncA(t+1) but its step-t readers finished
    // before syncB(t); xbuf[(t+1)&1] reads start post-syncB(t) ordering.
  }
}

extern "C" void kernel_launch(void* const* d_in, const int* in_sizes, int n_in,
                              void* d_out, int out_size, void* d_ws, size_t ws_size,
                              hipStream_t stream) {
  const float* x     = (const float*)d_in[0];
  const float* h0    = (const float*)d_in[1];
  const float* c0    = (const float*)d_in[2];
  const float* w_in  = (const float*)d_in[3];
  const float* biasp = (const float*)d_in[4];
  const float* w_rec = (const float*)d_in[5];
  float* outp = (float*)d_out;

  if (ws_size < (size_t)WS_NEEDED) return;

  uint8_t* ws = (uint8_t*)d_ws;
  ushort* xbp = (ushort*)(ws + WS_XBF);
  ushort* wcp = (ushort*)(ws + WS_WCAT);
  unsigned long long* hbp = (unsigned long long*)(ws + WS_HBUF);

  hipFuncSetAttribute(reinterpret_cast<const void*>(sublstm_main),
                      hipFuncAttributeMaxDynamicSharedMemorySize, LDS_SIZE);

  cvt_bf16_kernel<<<32768, 256, 0, stream>>>(x, xbp, 8388608);
  build_wcat_kernel<<<8192, 256, 0, stream>>>(w_in, w_rec, wcp);
  init_hbuf_kernel<<<256, 256, 0, stream>>>(h0, hbp);

  void* kargs[] = { (void*)&xbp, (void*)&wcp, (void*)&hbp,
                    (void*)&c0,  (void*)&biasp, (void*)&outp };
  hipLaunchCooperativeKernel((void*)sublstm_main, dim3(NBLK), dim3(512),
                             kargs, LDS_SIZE, stream);
}

// Round 8
// 2364.725 us; speedup vs baseline: 2.6231x; 2.6231x over previous
//
#include <hip/hip_runtime.h>
#include <hip/hip_bf16.h>
#include <stdint.h>

// SubLSTM: T=512, B=64, I=1024, H=1024, G=4096
// Persistent cooperative kernel. Round-8 = round-4 skeleton (tagged h words,
// all-thread batched poll, 2-slot rotation, swizzled LDS tiles, publish-first
// epilogue) + K-SPLIT-8 MFMA:
//   wave w computes ALL 4 gates over K-slice [w*256,(w+1)*256): A-fragments
//   read ONCE from LDS and reused 4x from registers -> block LDS reads/step
//   drop 256->64 (r4 read the 64KB tile with 4x redundancy; LDS-BW + bank
//   conflicts dominated its MFMA phase). A-regs live 2-at-a-time (not 8) to
//   stay under the 4-waves/SIMD register cliff (r7's spill lesson).
//   Gate exchange: gsm[gate][wave][cell] (32 KB); epilogue sums 8 partials.
// 256 blocks = 4 batch-groups(16 rows) x 64 unit-groups(16 units), 512 thr.

#define T_STEPS 512
#define NBLK 256

typedef short bf16x8 __attribute__((ext_vector_type(8)));
typedef float f32x4 __attribute__((ext_vector_type(4)));
typedef unsigned int u32x4 __attribute__((ext_vector_type(4)));

// ---- ws layout (bytes) ----
#define WS_XBF    0
#define WS_WCAT   67108864
#define WS_HBUF   83886080
#define WS_NEEDED (83886080 + 524288 + 256)

// ---- LDS layout (bytes) ----
#define LDS_X0   0          // x tiles, 2 x 32KB double buffer, swizzled
#define LDS_H    65536      // h tile, 32KB, swizzled
#define LDS_G    98304      // gate partials: [gate][wave][cell] f32 = 32KB
#define LDS_SIZE 131072

__device__ __forceinline__ ushort f2bf(float f) {
  uint32_t u = __float_as_uint(f);
  uint32_t r = (u + 0x7fffu + ((u >> 16) & 1u)) >> 16;
  return (ushort)r;
}

__device__ __forceinline__ float sigmoid_f(float x) {
  float e = __builtin_amdgcn_exp2f(-1.44269504f * x);
  return __builtin_amdgcn_rcpf(1.0f + e);
}

// 16B load bypassing L1+L2 (reads the coherence point / MALL).
__device__ __forceinline__ u32x4 poll_load16(const void* p) {
  u32x4 v;
  asm volatile("global_load_dwordx4 %0, %1, off sc0 sc1"
               : "=v"(v) : "v"(p));
  return v;
}
#define POLL_FENCE() do {                            \
    asm volatile("s_waitcnt vmcnt(0)" ::: "memory"); \
    __builtin_amdgcn_sched_barrier(0);               \
  } while (0)

__global__ void cvt_bf16_kernel(const float* __restrict__ src,
                                ushort* __restrict__ dst, int n4) {
  int i = blockIdx.x * 256 + threadIdx.x;
  if (i >= n4) return;
  float4 v = ((const float4*)src)[i];
  ushort4 o;
  o.x = f2bf(v.x); o.y = f2bf(v.y); o.z = f2bf(v.z); o.w = f2bf(v.w);
  ((ushort4*)dst)[i] = o;
}

// W_cat[g][0:1024] = W_in[g][:], W_cat[g][1024:2048] = W_rec[g][:]
__global__ void build_wcat_kernel(const float* __restrict__ w_in,
                                  const float* __restrict__ w_rec,
                                  ushort* __restrict__ wc) {
  int i = blockIdx.x * 256 + threadIdx.x;
  if (i >= (4096 * 2048) / 4) return;
  int col4 = i & 511;
  int g = i >> 9;
  const float* src = (col4 < 256) ? (w_in + (size_t)g * 1024 + col4 * 4)
                                  : (w_rec + (size_t)g * 1024 + (col4 - 256) * 4);
  float4 v = *(const float4*)src;
  ushort4 o;
  o.x = f2bf(v.x); o.y = f2bf(v.y); o.z = f2bf(v.z); o.w = f2bf(v.w);
  ((ushort4*)wc)[i] = o;
}

// slot0 <- h0 with tag 0; slot1 <- poison tag (never matches; tags 0..512)
__global__ void init_hbuf_kernel(const float* __restrict__ h0,
                                 unsigned long long* __restrict__ hb) {
  int i = blockIdx.x * 256 + threadIdx.x;  // 0..65535
  if (i >= 65536) return;
  if (i < 32768) {
    int row = i >> 9, u2 = i & 511;
    unsigned lo = f2bf(h0[(size_t)row * 1024 + u2 * 2]);
    unsigned hi = f2bf(h0[(size_t)row * 1024 + u2 * 2 + 1]);
    hb[i] = ((unsigned long long)((hi << 16) | lo) << 32) | 0ull;
  } else {
    hb[i] = 0xFFFFFFFFull;
  }
}

__launch_bounds__(512, 2)
__global__ void sublstm_main(const ushort* __restrict__ xb,
                             const ushort* __restrict__ wc,
                             unsigned long long* __restrict__ hb,
                             const float* __restrict__ c0,
                             const float* __restrict__ bias,
                             float* __restrict__ out) {
  extern __shared__ unsigned char smem[];
  float* gsm = (float*)(smem + LDS_G);

  const int tid  = threadIdx.x;
  const int lane = tid & 63;
  const int w    = tid >> 6;          // K-slice wave 0..7 (0-3 = x, 4-7 = h)
  const int bid  = blockIdx.x;
  const int b0   = (bid & 3) * 16;
  const int j0   = (bid >> 2) * 16;

  // ---- persistent weights: bfrag[gate n][k8] = W_cat row n*1024+j0+(lane&15),
  //      cols w*256 + k8*32 + (lane>>4)*8  (32 frags = 128 regs) ----
  bf16x8 bfrag[4][8];
  {
    const ushort* wbase =
        wc + (size_t)(j0 + (lane & 15)) * 2048 + w * 256 + ((lane >> 4) * 8);
#pragma unroll
    for (int n = 0; n < 4; ++n)
#pragma unroll
      for (int k8 = 0; k8 < 8; ++k8)
        bfrag[n][k8] =
            *(const bf16x8*)(wbase + (size_t)n * 2097152 + k8 * 32);
  }

  // ---- cell state + bias (threads 0..255: (batch bb, unit uu)) ----
  const int bb = tid >> 4, uu = tid & 15;
  float c_reg = 0.f;
  float bias_r0 = 0.f, bias_r1 = 0.f, bias_r2 = 0.f, bias_r3 = 0.f;
  if (tid < 256) {
    c_reg = c0[(size_t)(b0 + bb) * 1024 + j0 + uu];
    bias_r0 = bias[0 * 1024 + j0 + uu];
    bias_r1 = bias[1 * 1024 + j0 + uu];
    bias_r2 = bias[2 * 1024 + j0 + uu];
    bias_r3 = bias[3 * 1024 + j0 + uu];
  }

  // ---- fixed addressing (identical to round-4) ----
  const int prow = tid >> 5;                  // h-poll row 0..15
  const int pc   = tid & 31;                  // h-poll chunk-lane 0..31
  const int arow = lane & 15;
  const int aswz = (arow & 7) << 4;
  const int pswz = (prow & 7) << 4;
  const int basew2 = (b0 + prow) * 512 + pc * 2;   // 8B-word idx (16B aligned)
  const int hbyte  = prow * 2048 + pc * 8;         // LDS byte base for staging
  // A-read base: this wave's K-slice within x (w<4) or h (w>=4) tile
  const int aoff = arow * 2048 + ((lane >> 4) * 16);
  const int abase_nox = (w < 4 ? w * 512 : LDS_H + (w - 4) * 512) + aoff;

  // ---- prologue: stage x_0 into buffer 0 ----
  {
    const ushort* xrow = xb + (size_t)b0 * 1024;
#pragma unroll
    for (int j = 0; j < 4; ++j) {
      int L = (tid + j * 512) * 16;            // 0..32767
      int row = L >> 11;
      int colb = L & 2047;
      uint4 v = *(const uint4*)(xrow + (size_t)row * 1024 + (colb >> 1));
      *(uint4*)(smem + (L ^ ((row & 7) << 4))) = v;
    }
  }

  for (int t = 0; t < T_STEPS; ++t) {
    // ---- poll h_t: 8 x dwordx4, batched re-poll of pending chunks only ----
    {
      const unsigned long long* pb = hb + ((t & 1) << 15) + basew2;
      u32x4 vv[8];
#pragma unroll
      for (int i = 0; i < 8; ++i) vv[i] = poll_load16(pb + i * 64);
      POLL_FENCE();
      for (;;) {
        unsigned np = 0;
#pragma unroll
        for (int i = 0; i < 8; ++i)
          if ((vv[i].x != (unsigned)t) || (vv[i].z != (unsigned)t))
            np |= (1u << i);
        if (!np) break;
        __builtin_amdgcn_s_sleep(1);
#pragma unroll
        for (int i = 0; i < 8; ++i)
          if (np & (1u << i)) vv[i] = poll_load16(pb + i * 64);
        POLL_FENCE();
      }
      // stage data dwords (2 x bf16 each) -> swizzled LDS h tile
#pragma unroll
      for (int i = 0; i < 8; ++i) {
        uint2 d; d.x = vv[i].y; d.y = vv[i].w;
        *(uint2*)(smem + LDS_H + ((hbyte + i * 256) ^ pswz)) = d;
      }
    }
    __syncthreads();   // syncA: h staged (x staged last step / prologue)

    // ---- MFMA: this wave's K-slice (256), ALL 4 gates; A reused 4x ----
    const int abase = abase_nox + ((w < 4) ? ((t & 1) << 15) : 0);
    f32x4 acc0 = {0,0,0,0}, acc1 = {0,0,0,0}, acc2 = {0,0,0,0}, acc3 = {0,0,0,0};
#pragma unroll
    for (int k8 = 0; k8 < 8; k8 += 2) {
      bf16x8 a0 = *(const bf16x8*)(smem + ((abase + k8 * 64) ^ aswz));
      bf16x8 a1 = *(const bf16x8*)(smem + ((abase + (k8 + 1) * 64) ^ aswz));
      acc0 = __builtin_amdgcn_mfma_f32_16x16x32_bf16(a0, bfrag[0][k8], acc0, 0, 0, 0);
      acc1 = __builtin_amdgcn_mfma_f32_16x16x32_bf16(a0, bfrag[1][k8], acc1, 0, 0, 0);
      acc2 = __builtin_amdgcn_mfma_f32_16x16x32_bf16(a0, bfrag[2][k8], acc2, 0, 0, 0);
      acc3 = __builtin_amdgcn_mfma_f32_16x16x32_bf16(a0, bfrag[3][k8], acc3, 0, 0, 0);
      acc0 = __builtin_amdgcn_mfma_f32_16x16x32_bf16(a1, bfrag[0][k8 + 1], acc0, 0, 0, 0);
      acc1 = __builtin_amdgcn_mfma_f32_16x16x32_bf16(a1, bfrag[1][k8 + 1], acc1, 0, 0, 0);
      acc2 = __builtin_amdgcn_mfma_f32_16x16x32_bf16(a1, bfrag[2][k8 + 1], acc2, 0, 0, 0);
      acc3 = __builtin_amdgcn_mfma_f32_16x16x32_bf16(a1, bfrag[3][k8 + 1], acc3, 0, 0, 0);
    }

    // ---- gate partials -> gsm[gate][wave][cell] ----
#pragma unroll
    for (int r = 0; r < 4; ++r) {
      int cell = ((lane >> 4) * 4 + r) * 16 + (lane & 15);
      gsm[0 * 2048 + w * 256 + cell] = acc0[r];
      gsm[1 * 2048 + w * 256 + cell] = acc1[r];
      gsm[2 * 2048 + w * 256 + cell] = acc2[r];
      gsm[3 * 2048 + w * 256 + cell] = acc3[r];
    }
    __syncthreads();   // syncB: all partials in; LDS tile reads done

    // ---- cell update; publish h FIRST, then out (threads 0..255) ----
    if (tid < 256) {
      float p0 = bias_r0, p1 = bias_r1, p2 = bias_r2, p3 = bias_r3;
#pragma unroll
      for (int w8 = 0; w8 < 8; ++w8) {
        p0 += gsm[0 * 2048 + w8 * 256 + tid];
        p1 += gsm[1 * 2048 + w8 * 256 + tid];
        p2 += gsm[2 * 2048 + w8 * 256 + tid];
        p3 += gsm[3 * 2048 + w8 * 256 + tid];
      }
      float g_in  = sigmoid_f(p0);
      float g_out = sigmoid_f(p1);
      float g_z   = sigmoid_f(p2);
      float g_f   = sigmoid_f(p3);
      c_reg = c_reg * g_f + g_z - g_in;
      float h_new = sigmoid_f(c_reg) - g_out;

      unsigned hbits = (unsigned)f2bf(h_new);
      unsigned pv = (unsigned)__shfl_xor((int)hbits, 1);
      if ((uu & 1) == 0) {
        unsigned hi32 = (pv << 16) | hbits;
        int wi = ((1 - (t & 1)) << 15) + (b0 + bb) * 512 + ((j0 + uu) >> 1);
        __hip_atomic_store(&hb[wi],
                           ((unsigned long long)hi32 << 32) |
                               (unsigned long long)(unsigned)(t + 1),
                           __ATOMIC_RELAXED, __HIP_MEMORY_SCOPE_AGENT);
      }
      size_t oidx = (size_t)(b0 + bb) * 1024 + j0 + uu;
      out[(size_t)t * 65536 + oidx] = h_new;
      if (t == T_STEPS - 1) {
        out[(size_t)T_STEPS * 65536 + oidx] = h_new;           // hT
        out[(size_t)T_STEPS * 65536 + 65536 + oidx] = c_reg;   // cT
      }
    }

    // ---- stage x_{t+1} (off critical path; protected by syncA(t+1)) ----
    if (t + 1 < T_STEPS) {
      const ushort* xrow = xb + ((size_t)(t + 1) * 64 + b0) * 1024;
      const int xo = ((t + 1) & 1) << 15;
#pragma unroll
      for (int j = 0; j < 4; ++j) {
        int L = (tid + j * 512) * 16;
        int row = L >> 11;
        int colb = L & 2047;
        uint4 v = *(const uint4*)(xrow + (size_t)row * 1024 + (colb >> 1));
        *(uint4*)(smem + xo + (L ^ ((row & 7) << 4))) = v;
      }
    }
    // no loop-end barrier: staging writes for t+1 only touch regions whose
    // step-t readers finished before syncB(t); gsm reads of step t complete
    // before this thread reaches syncA(t+1).
  }
}

extern "C" void kernel_launch(void* const* d_in, const int* in_sizes, int n_in,
                              void* d_out, int out_size, void* d_ws, size_t ws_size,
                              hipStream_t stream) {
  const float* x     = (const float*)d_in[0];
  const float* h0    = (const float*)d_in[1];
  const float* c0    = (const float*)d_in[2];
  const float* w_in  = (const float*)d_in[3];
  const float* biasp = (const float*)d_in[4];
  const float* w_rec = (const float*)d_in[5];
  float* outp = (float*)d_out;

  if (ws_size < (size_t)WS_NEEDED) return;

  uint8_t* ws = (uint8_t*)d_ws;
  ushort* xbp = (ushort*)(ws + WS_XBF);
  ushort* wcp = (ushort*)(ws + WS_WCAT);
  unsigned long long* hbp = (unsigned long long*)(ws + WS_HBUF);

  hipFuncSetAttribute(reinterpret_cast<const void*>(sublstm_main),
                      hipFuncAttributeMaxDynamicSharedMemorySize, LDS_SIZE);

  cvt_bf16_kernel<<<32768, 256, 0, stream>>>(x, xbp, 8388608);
  build_wcat_kernel<<<8192, 256, 0, stream>>>(w_in, w_rec, wcp);
  init_hbuf_kernel<<<256, 256, 0, stream>>>(h0, hbp);

  void* kargs[] = { (void*)&xbp, (void*)&wcp, (void*)&hbp,
                    (void*)&c0,  (void*)&biasp, (void*)&outp };
  hipLaunchCooperativeKernel((void*)sublstm_main, dim3(NBLK), dim3(512),
                             kargs, LDS_SIZE, stream);
}